// Round 4
// baseline (2471.145 us; speedup 1.0000x reference)
//
#include <hip/hip_runtime.h>
#include <cstdint>
#include <cstddef>

#define CMID 512

typedef __bf16 bf16x8 __attribute__((ext_vector_type(8)));
typedef float  f32x4  __attribute__((ext_vector_type(4)));

__device__ __forceinline__ ushort f2bf(float v) {
  unsigned u = __float_as_uint(v);
  unsigned r = (u + 0x7fffu + ((u >> 16) & 1u)) >> 16;   // RNE
  return (ushort)r;
}

// async global->LDS DMA, 16B per lane; LDS dest must be wave-uniform base,
// lane i lands at base + i*16 (linear). Global src IS per-lane.
__device__ __forceinline__ void async_copy16(void* lds, const void* g) {
  __builtin_amdgcn_global_load_lds(
      (const __attribute__((address_space(1))) unsigned int*)g,
      (__attribute__((address_space(3))) unsigned int*)lds, 16, 0, 0);
}

// ---- W [27][Cin][512] f32  ->  wT [27][512][Cin] bf16 ----------------------
__global__ __launch_bounds__(256) void transpose_w_kernel(
    const float* __restrict__ W, ushort* __restrict__ wT, int Cin)
{
  __shared__ float tile[32][33];
  int k = blockIdx.z;
  int ci0 = blockIdx.x * 32, co0 = blockIdx.y * 32;
  int tx = threadIdx.x & 31, ty = threadIdx.x >> 5;
  const float* src = W + ((size_t)k * Cin + ci0) * CMID + co0;
  for (int r = ty; r < 32; r += 8)
    tile[r][tx] = src[(size_t)r * CMID + tx];
  __syncthreads();
  ushort* dst = wT + ((size_t)k * CMID + co0) * Cin + ci0;
  for (int r = ty; r < 32; r += 8)
    dst[(size_t)r * Cin + tx] = f2bf(tile[tx][r]);
}

// ---- build inverse kernel map: inv[k][o] = in_idx (or -1) -----------------
__global__ __launch_bounds__(256) void build_inv_kernel(
    const int* __restrict__ in_map, const int* __restrict__ out_map,
    int* __restrict__ inv, int P, int n_out)
{
  int i = blockIdx.x * 256 + threadIdx.x;
  if (i >= 27 * P) return;
  int o = out_map[i];
  if (o < n_out) inv[(size_t)(i / P) * n_out + o] = in_map[i];
}

// ---- OUTPUT-STATIONARY conv (level 2) -------------------------------------
// Round-4: XCD group swizzle. 1-D grid = 64*ceil(G/8), G = ceil(n_out/128).
// All 8 (j0,z) blocks of one o-group map to linear IDs == same (mod 8), so
// round-robin dispatch puts them on ONE XCD: the 27*128-row A-gather (628 MB
// of the 637 MB measured FETCH) is fetched once per group into that XCD's L2
// instead of up to 8x across XCDs.
// Staging via global_load_lds dwordx4; linear [128][64] LDS, XOR chunk
// swizzle applied BOTH on per-lane global source chunk and ds_read address.
// Invalid gather rows (-1) redirect to zeroed row `zrow`.
// z-halves combine via fp32 atomicAdd into pre-zeroed accum.
__global__ __launch_bounds__(256, 4) void conv_os(
    const ushort* __restrict__ x, const ushort* __restrict__ wT,
    const int* __restrict__ inv, float* __restrict__ out,
    int n_out, int C_in, int zrow)
{
  const int G   = (n_out + 127) >> 7;
  const int b   = (int)blockIdx.x;
  const int xcd = b & 7;
  const int tt  = b >> 3;
  const int gh  = tt >> 3;
  const int ii  = tt & 7;
  const int g   = gh * 8 + xcd;
  if (g >= G) return;                    // tail pad (uniform per block)

  const int o0  = g * 128;
  const int j0  = (ii & 3) * 128;
  const int kb0 = (ii >> 2) * 256;       // half of C_in=512
  const int t   = threadIdx.x;

  __shared__ int in_s[128];
  __shared__ ushort A_s[128][64];        // linear: DMA dest (1KB/instr/wave)
  __shared__ ushort B_s[128][64];

  const int lane = t & 63;
  const int wv   = t >> 6;
  const int wm   = (wv & 1) * 64;
  const int wn   = (wv >> 1) * 64;
  const int ml   = lane & 15;
  const int q    = lane >> 4;
  const int srow = lane >> 3;            // row-within-DMA-instr 0..7
  const int gch  = (lane & 7) ^ srow;    // swizzled source chunk (16B units)

  f32x4 acc[4][4] = {};

  for (int k = 0; k < 27; ++k) {
    if (t < 128) {
      int o = o0 + t;
      int s = (o < n_out) ? inv[(size_t)k * n_out + o] : -1;
      in_s[t] = (s >= 0) ? s : zrow;     // zrow is a zeroed feature row
    }
    __syncthreads();

    const ushort* wk = wT + ((size_t)k * CMID + j0) * C_in;
    const ushort* abase[4];
    const ushort* bbase[4];
#pragma unroll
    for (int j = 0; j < 4; ++j) {
      int row = wv * 32 + j * 8 + srow;
      abase[j] = x  + (size_t)in_s[row] * C_in + kb0 + gch * 8;
      bbase[j] = wk + (size_t)row       * C_in + kb0 + gch * 8;
    }

    for (int kb = 0; kb < 256; kb += 64) {
#pragma unroll
      for (int j = 0; j < 4; ++j) {
        async_copy16(&A_s[wv * 32 + j * 8][0], abase[j] + kb);
        async_copy16(&B_s[wv * 32 + j * 8][0], bbase[j] + kb);
      }
      __syncthreads();                   // compiler drains vmcnt before barrier
#pragma unroll
      for (int ks = 0; ks < 2; ++ks) {
        const int c = ((ks << 2) | q) ^ (ml & 7);   // swizzled read chunk
        bf16x8 af[4], bb[4];
#pragma unroll
        for (int mt = 0; mt < 4; ++mt)
          af[mt] = *(const bf16x8*)&A_s[wm + mt * 16 + ml][c << 3];
#pragma unroll
        for (int nt = 0; nt < 4; ++nt)
          bb[nt] = *(const bf16x8*)&B_s[wn + nt * 16 + ml][c << 3];
#pragma unroll
        for (int mt = 0; mt < 4; ++mt)
#pragma unroll
          for (int nt = 0; nt < 4; ++nt)
            acc[mt][nt] = __builtin_amdgcn_mfma_f32_16x16x32_bf16(
                af[mt], bb[nt], acc[mt][nt], 0, 0, 0);
      }
      __syncthreads();                   // guards A_s/B_s overwrite next kb
    }
  }

  // C/D layout: col = lane&15, row = (lane>>4)*4 + reg   [m89-verified]
#pragma unroll
  for (int mt = 0; mt < 4; ++mt) {
#pragma unroll
    for (int r = 0; r < 4; ++r) {
      int o = o0 + wm + mt * 16 + q * 4 + r;
      if (o < n_out) {
        float* orow = out + (size_t)o * CMID + j0 + wn + ml;
#pragma unroll
        for (int nt = 0; nt < 4; ++nt)
          atomicAdd(orow + nt * 16, acc[mt][nt][r]);
      }
    }
  }
}

// ---- center conv (level 1, k=13 identity): plain stores = accum init ------
__global__ __launch_bounds__(256, 4) void conv_center(
    const ushort* __restrict__ x, const ushort* __restrict__ wT,
    float* __restrict__ out, int n_out, int C_in)
{
  const int k  = 13;
  const int p0 = blockIdx.x * 128;
  const int j0 = blockIdx.y * 128;
  const int t  = threadIdx.x;

  __shared__ ushort A_s[128][64];
  __shared__ ushort B_s[128][64];

  const int lane = t & 63;
  const int wv   = t >> 6;
  const int wm   = (wv & 1) * 64;
  const int wn   = (wv >> 1) * 64;
  const int ml   = lane & 15;
  const int q    = lane >> 4;
  const int srow = lane >> 3;
  const int gch  = (lane & 7) ^ srow;

  const ushort* wk = wT + ((size_t)k * CMID + j0) * C_in;
  const ushort* abase[4];
  const ushort* bbase[4];
#pragma unroll
  for (int j = 0; j < 4; ++j) {
    int row = wv * 32 + j * 8 + srow;
    int src = p0 + row; if (src >= n_out) src = n_out - 1;
    abase[j] = x  + (size_t)src * C_in + gch * 8;
    bbase[j] = wk + (size_t)row * C_in + gch * 8;
  }

  f32x4 acc[4][4] = {};

  for (int kb = 0; kb < C_in; kb += 64) {
#pragma unroll
    for (int j = 0; j < 4; ++j) {
      async_copy16(&A_s[wv * 32 + j * 8][0], abase[j] + kb);
      async_copy16(&B_s[wv * 32 + j * 8][0], bbase[j] + kb);
    }
    __syncthreads();
#pragma unroll
    for (int ks = 0; ks < 2; ++ks) {
      const int c = ((ks << 2) | q) ^ (ml & 7);
      bf16x8 af[4], bb[4];
#pragma unroll
      for (int mt = 0; mt < 4; ++mt)
        af[mt] = *(const bf16x8*)&A_s[wm + mt * 16 + ml][c << 3];
#pragma unroll
      for (int nt = 0; nt < 4; ++nt)
        bb[nt] = *(const bf16x8*)&B_s[wn + nt * 16 + ml][c << 3];
#pragma unroll
      for (int mt = 0; mt < 4; ++mt)
#pragma unroll
        for (int nt = 0; nt < 4; ++nt)
          acc[mt][nt] = __builtin_amdgcn_mfma_f32_16x16x32_bf16(
              af[mt], bb[nt], acc[mt][nt], 0, 0, 0);
    }
    __syncthreads();
  }

#pragma unroll
  for (int mt = 0; mt < 4; ++mt) {
#pragma unroll
    for (int r = 0; r < 4; ++r) {
      int o = p0 + wm + mt * 16 + q * 4 + r;
      if (o < n_out) {
        float* orow = out + (size_t)o * CMID + j0 + wn + ml;
#pragma unroll
        for (int nt = 0; nt < 4; ++nt) orow[nt * 16] = acc[mt][nt][r];
      }
    }
  }
}

// ---- level-1 off-center scatter conv --------------------------------------
// Round-4: XCD group swizzle. 104 (j0,k) groups = 8 XCDs x 13; all XT x-tiles
// of one group land on one XCD -> the shared 128KB B-tile stays L2-resident
// (was fetched by up to 8 XCDs). Per-group x-tile rotation keeps concurrent
// same-XCD groups writing different output regions; same-XCD atomic
// collisions resolve in the local L2 instead of bouncing lines cross-XCD.
// Grid: 1-D, 104 * XT blocks, XT = ceil(P/128).
__global__ __launch_bounds__(256, 4) void conv_scatter(
    const ushort* __restrict__ x, const ushort* __restrict__ wT,
    const int* __restrict__ in_map, const int* __restrict__ out_map,
    float* __restrict__ out, int P, int n_out, int C_in)
{
  const int XT  = (int)gridDim.x / 104;
  const int b   = (int)blockIdx.x;
  const int xcd = b & 7;
  const int s   = b >> 3;                // [0, 13*XT)
  const int kjl = s / XT;                // [0, 13)
  const int i0  = s - kjl * XT;          // [0, XT)
  const int kj  = xcd * 13 + kjl;        // [0, 104)
  const int kz  = kj % 26;
  const int k   = kz + (kz >= 13);
  const int j0  = (kj / 26) * 128;
  const int it  = (i0 + kjl * 5) % XT;   // rotate: decorrelate atomic regions
  const int p0  = it * 128;
  const int t   = threadIdx.x;

  __shared__ int out_s[128];
  __shared__ int in_s[128];
  __shared__ int anyv;
  __shared__ ushort A_s[128][64];
  __shared__ ushort B_s[128][64];

  if (t == 0) anyv = 0;
  __syncthreads();
  if (t < 128) {
    int p  = p0 + t;
    int oi = (p < P) ? out_map[(size_t)k * P + p] : n_out;
    int ii = (p < P) ? in_map[(size_t)k * P + p]  : 0;
    out_s[t] = oi; in_s[t] = ii;
    if (oi < n_out) anyv = 1;
  }
  __syncthreads();
  if (!anyv) return;

  const int lane = t & 63;
  const int wv   = t >> 6;
  const int wm   = (wv & 1) * 64;
  const int wn   = (wv >> 1) * 64;
  const int ml   = lane & 15;
  const int q    = lane >> 4;
  const int srow = lane >> 3;
  const int gch  = (lane & 7) ^ srow;

  const ushort* wk = wT + ((size_t)k * CMID + j0) * C_in;
  const ushort* abase[4];
  const ushort* bbase[4];
#pragma unroll
  for (int j = 0; j < 4; ++j) {
    int row = wv * 32 + j * 8 + srow;
    abase[j] = x  + (size_t)in_s[row] * C_in + gch * 8;
    bbase[j] = wk + (size_t)row       * C_in + gch * 8;
  }

  f32x4 acc[4][4] = {};

  for (int kb = 0; kb < C_in; kb += 64) {
#pragma unroll
    for (int j = 0; j < 4; ++j) {
      async_copy16(&A_s[wv * 32 + j * 8][0], abase[j] + kb);
      async_copy16(&B_s[wv * 32 + j * 8][0], bbase[j] + kb);
    }
    __syncthreads();
#pragma unroll
    for (int ks = 0; ks < 2; ++ks) {
      const int c = ((ks << 2) | q) ^ (ml & 7);
      bf16x8 af[4], bb[4];
#pragma unroll
      for (int mt = 0; mt < 4; ++mt)
        af[mt] = *(const bf16x8*)&A_s[wm + mt * 16 + ml][c << 3];
#pragma unroll
      for (int nt = 0; nt < 4; ++nt)
        bb[nt] = *(const bf16x8*)&B_s[wn + nt * 16 + ml][c << 3];
#pragma unroll
      for (int mt = 0; mt < 4; ++mt)
#pragma unroll
        for (int nt = 0; nt < 4; ++nt)
          acc[mt][nt] = __builtin_amdgcn_mfma_f32_16x16x32_bf16(
              af[mt], bb[nt], acc[mt][nt], 0, 0, 0);
    }
    __syncthreads();
  }

#pragma unroll
  for (int mt = 0; mt < 4; ++mt) {
#pragma unroll
    for (int r = 0; r < 4; ++r) {
      int o = out_s[wm + mt * 16 + q * 4 + r];
      if (o < n_out) {
        float* orow = out + (size_t)o * CMID + j0 + wn + ml;
#pragma unroll
        for (int nt = 0; nt < 4; ++nt)
          atomicAdd(orow + nt * 16, acc[mt][nt][r]);
      }
    }
  }
}

// ---- BN stats (fp32 accum) ------------------------------------------------
__global__ __launch_bounds__(256) void bn_stats_kernel(
    const float* __restrict__ x, float* __restrict__ stats, int n)
{
  int t = threadIdx.x;
  float s0 = 0.f, q0 = 0.f, s1 = 0.f, q1 = 0.f;
  for (int r = blockIdx.x; r < n; r += gridDim.x) {
    const float* row = x + (size_t)r * CMID;
    float v0 = row[t];
    float v1 = row[t + 256];
    s0 += v0; q0 += v0 * v0;
    s1 += v1; q1 += v1 * v1;
  }
  atomicAdd(&stats[t],        s0);
  atomicAdd(&stats[512 + t],  q0);
  atomicAdd(&stats[t + 256],  s1);
  atomicAdd(&stats[768 + t],  q1);
}

// ---- BN apply + ReLU, fp32 in -> bf16 out; optional fused max-pool --------
__global__ __launch_bounds__(256) void bn_apply_cast(
    const float* __restrict__ x, const float* __restrict__ stats,
    const float* __restrict__ gamma, const float* __restrict__ beta,
    ushort* __restrict__ y, long total, float inv_n,
    const int* __restrict__ pidx, float* __restrict__ pout)
{
  long stride = (long)gridDim.x * 256;
  for (long i = (long)blockIdx.x * 256 + threadIdx.x; i < total; i += stride) {
    int c = (int)(i & 511);
    float mu  = stats[c] * inv_n;
    float var = stats[512 + c] * inv_n - mu * mu;
    float g   = gamma[c] * rsqrtf(var + 1e-5f);
    float v   = (x[i] - mu) * g + beta[c];
    ushort yv = f2bf(v > 0.f ? v : 0.f);
    y[i] = yv;
    if (pout) {
      int r = (int)(i >> 9);
      int o = pidx[r];
      atomicMax((int*)(pout + (size_t)o * CMID + c), ((int)yv) << 16);
    }
  }
}

// ---- pools (post-ReLU >= 0 -> int-punned atomicMax), grid-stride ----------
__global__ __launch_bounds__(256) void pool_max_bf16(
    const ushort* __restrict__ x, const int* __restrict__ idx,
    float* __restrict__ out, long total)
{
  long stride = (long)gridDim.x * 256;
  for (long i = (long)blockIdx.x * 256 + threadIdx.x; i < total; i += stride) {
    int r = (int)(i >> 9);
    int c = (int)(i & 511);
    int o = idx[r];
    int bits = ((int)x[i]) << 16;
    atomicMax((int*)(out + (size_t)o * CMID + c), bits);
  }
}

__global__ __launch_bounds__(256) void pool_max_f32(
    const float* __restrict__ x, const int* __restrict__ idx,
    float* __restrict__ out, long total)
{
  long stride = (long)gridDim.x * 256;
  for (long i = (long)blockIdx.x * 256 + threadIdx.x; i < total; i += stride) {
    int r = (int)(i >> 9);
    int c = (int)(i & 511);
    int o = idx[r];
    atomicMax((int*)(out + (size_t)o * CMID + c), __float_as_int(x[i]));
  }
}

// ---- cast fp32 -> bf16, grid-stride ---------------------------------------
__global__ __launch_bounds__(256) void cast_f32_bf16_kernel(
    const float* __restrict__ in, ushort* __restrict__ out, long n)
{
  long stride = (long)gridDim.x * 256;
  for (long i = (long)blockIdx.x * 256 + threadIdx.x; i < n; i += stride)
    out[i] = f2bf(in[i]);
}

// ---- FC: partial GEMM with K-split ----------------------------------------
__global__ __launch_bounds__(256) void fc_partial(
    const float* __restrict__ x, const float* __restrict__ W,
    float* __restrict__ h, int K, int N, int Kc)
{
  __shared__ float xs[8][1024];
  int t  = threadIdx.x;
  int j  = blockIdx.x * 64 + (t & 63);
  int bg = t >> 6;
  int k0 = blockIdx.y * Kc;
  for (int i = t; i < 8 * Kc; i += 256) {
    int b = i / Kc; int kk = i - b * Kc;
    xs[b][kk] = x[(size_t)b * K + k0 + kk];
  }
  __syncthreads();
  float a0 = 0.f, a1 = 0.f;
  for (int kk = 0; kk < Kc; ++kk) {
    float wv = W[(size_t)(k0 + kk) * N + j];
    a0 += xs[bg][kk] * wv;
    a1 += xs[bg + 4][kk] * wv;
  }
  atomicAdd(&h[(size_t)bg * N + j], a0);
  atomicAdd(&h[(size_t)(bg + 4) * N + j], a1);
}

__global__ __launch_bounds__(256) void bias_relu_kernel(
    float* __restrict__ h, const float* __restrict__ bias, int N)
{
  int i = blockIdx.x * 256 + threadIdx.x;
  if (i >= 8 * N) return;
  float v = h[i] + bias[i % N];
  h[i] = v > 0.f ? v : 0.f;
}

// ---- FC3 -------------------------------------------------------------------
__global__ __launch_bounds__(320) void fc3_kernel(
    const float* __restrict__ x, const float* __restrict__ W,
    const float* __restrict__ bias, float* __restrict__ out)
{
  int t = threadIdx.x;
  int j = t % 40;
  int b = t / 40;
  int kb = blockIdx.x * 128;
  float acc = 0.f;
#pragma unroll 8
  for (int kk = 0; kk < 128; ++kk)
    acc += x[(size_t)b * 4096 + kb + kk] * W[(size_t)(kb + kk) * 40 + j];
  if (blockIdx.x == 0) acc += bias[j];
  atomicAdd(&out[(size_t)b * 40 + j], acc);
}

// ---------------------------------------------------------------------------
extern "C" void kernel_launch(void* const* d_in, const int* in_sizes, int n_in,
                              void* d_out, int out_size, void* d_ws, size_t ws_size,
                              hipStream_t stream)
{
  const float* feats  = (const float*)d_in[0];
  const float* wts[6] = {(const float*)d_in[1], (const float*)d_in[2],
                         (const float*)d_in[3], (const float*)d_in[4],
                         (const float*)d_in[5], (const float*)d_in[6]};
  const float* bn_g   = (const float*)d_in[7];
  const float* bn_b   = (const float*)d_in[8];
  const float* fc1_w  = (const float*)d_in[9];
  const float* fc1_b  = (const float*)d_in[10];
  const float* fc2_w  = (const float*)d_in[11];
  const float* fc2_b  = (const float*)d_in[12];
  const float* fc3_w  = (const float*)d_in[13];
  const float* fc3_b  = (const float*)d_in[14];
  const int* map1_in  = (const int*)d_in[15];
  const int* map1_out = (const int*)d_in[16];
  const int* map2_in  = (const int*)d_in[17];
  const int* map2_out = (const int*)d_in[18];
  const int* pool1_idx = (const int*)d_in[19];
  const int* pool2_idx = (const int*)d_in[20];
  const int* batch_idx = (const int*)d_in[21];

  const int N1 = in_sizes[0] / 256;
  const int P1 = in_sizes[15] / 27;
  const int P2 = in_sizes[17] / 27;
  const int n2 = in_sizes[20];
  const int n3 = in_sizes[21];

  // workspace layout (~126.3 MiB used of >=128):
  //  [0,64)    accum fp32 (N1 x 512) / pool1 target
  //  [64,96)   fbuf bf16 features (post-BN); row n2 kept zero (conv_os zrow)
  //  [96,112)  featsb bf16 conv1 input; later: pooled2f (fp32, <=8.5 MB)
  //            + inv2 (27 x n2 ints, ~2.3 MB) at +9 MiB
  //  [112,126) wTbuf bf16 transposed weights
  //  [126,..)  stats + FC scratch
  const size_t MB = (size_t)1 << 20;
  char* wsb = (char*)d_ws;
  float*  accum   = (float*)wsb;
  ushort* fbuf    = (ushort*)(wsb + 64 * MB);
  ushort* featsb  = (ushort*)(wsb + 96 * MB);
  int*    inv2    = (int*)(wsb + 105 * MB);
  ushort* wTbuf   = (ushort*)(wsb + 112 * MB);
  float*  stats   = (float*)(wsb + 126 * MB);
  float*  gpooled = stats + 1024;
  float*  h1      = gpooled + 8 * 512;
  float*  h2      = h1 + 8 * 4096;
  float*  pooled2f = (float*)featsb;

  auto gsb = [](long tot) {                 // grid-stride block count, G11 cap
    long b = (tot + 255) / 256;
    return (int)(b < 2048 ? b : 2048);
  };

  long nf = (long)N1 * 256;
  cast_f32_bf16_kernel<<<gsb(nf), 256, 0, stream>>>(feats, featsb, nf);

  const int XT1 = (P1 + 127) / 128;

  // level-1 conv: center (plain stores, inits accum) + 26 scatter offsets
  auto conv1 = [&](const ushort* xin, const float* w, int Cin) {
    transpose_w_kernel<<<dim3(Cin / 32, CMID / 32, 27), 256, 0, stream>>>(w, wTbuf, Cin);
    conv_center<<<dim3((N1 + 127) / 128, 4, 1), 256, 0, stream>>>(
        xin, wTbuf, accum, N1, Cin);
    conv_scatter<<<104 * XT1, 256, 0, stream>>>(
        xin, wTbuf, map1_in, map1_out, accum, P1, N1, Cin);
  };
  // level-2 conv: output-stationary, K-split z=2, atomic fp32 combine
  const int G2 = (n2 + 127) / 128;
  auto conv2 = [&](const ushort* xin, const float* w) {
    transpose_w_kernel<<<dim3(512 / 32, CMID / 32, 27), 256, 0, stream>>>(w, wTbuf, 512);
    hipMemsetAsync(accum, 0, (size_t)n2 * CMID * sizeof(float), stream);
    conv_os<<<64 * ((G2 + 7) / 8), 256, 0, stream>>>(
        xin, wTbuf, inv2, accum, n2, 512, n2);
  };
  auto bn = [&](int layer, int n, const int* pidx, float* pout) {
    hipMemsetAsync(stats, 0, 1024 * sizeof(float), stream);
    bn_stats_kernel<<<1024, 256, 0, stream>>>(accum, stats, n);
    long tot = (long)n * CMID;
    bn_apply_cast<<<gsb(tot), 256, 0, stream>>>(
        accum, stats, bn_g + layer * CMID, bn_b + layer * CMID, fbuf, tot,
        1.0f / n, pidx, pout);
  };

  // --- level 1 ---
  conv1(featsb, wts[0], 256); bn(0, N1, nullptr, nullptr);
  conv1(fbuf,   wts[1], 512); bn(1, N1, nullptr, nullptr);
  conv1(fbuf,   wts[2], 512); bn(2, N1, nullptr, nullptr);

  // --- pool 1: fbuf(N1) -> accum(n2, fp32) -> fbuf bf16 ---
  long t1 = (long)N1 * CMID;
  long t2 = (long)n2 * CMID;
  hipMemsetAsync(accum, 0, (size_t)n2 * CMID * sizeof(float), stream);
  pool_max_bf16<<<gsb(t1), 256, 0, stream>>>(fbuf, pool1_idx, accum, t1);
  cast_f32_bf16_kernel<<<gsb(t2), 256, 0, stream>>>(accum, fbuf, t2);
  // zero row n2 of fbuf: conv_os redirects invalid gathers here (DMA can't
  // predicate). bn_apply_cast only writes rows < n2, so it stays zero.
  hipMemsetAsync(fbuf + (size_t)n2 * CMID, 0, CMID * sizeof(ushort), stream);

  // --- build level-2 inverse map (once; reused by all 3 convs) ---
  hipMemsetAsync(inv2, 0xFF, (size_t)27 * n2 * sizeof(int), stream);
  build_inv_kernel<<<(27 * P2 + 255) / 256, 256, 0, stream>>>(
      map2_in, map2_out, inv2, P2, n2);

  // --- level 2 (output-stationary); pool2 fused into last bn ---
  conv2(fbuf, wts[3]); bn(3, n2, nullptr, nullptr);
  conv2(fbuf, wts[4]); bn(4, n2, nullptr, nullptr);
  conv2(fbuf, wts[5]);
  hipMemsetAsync(pooled2f, 0, (size_t)n3 * CMID * sizeof(float), stream);
  bn(5, n2, pool2_idx, pooled2f);   // bn + ReLU + cast + pool2 in one pass

  // --- global max pool ---
  long t3 = (long)n3 * CMID;
  hipMemsetAsync(gpooled, 0, 8 * CMID * sizeof(float), stream);
  pool_max_f32<<<gsb(t3), 256, 0, stream>>>(pooled2f, batch_idx, gpooled, t3);

  // --- FC head ---
  hipMemsetAsync(h1, 0, 8 * 4096 * sizeof(float), stream);
  fc_partial<<<dim3(64, 1), 256, 0, stream>>>(gpooled, fc1_w, h1, 512, 4096, 512);
  bias_relu_kernel<<<128, 256, 0, stream>>>(h1, fc1_b, 4096);
  hipMemsetAsync(h2, 0, 8 * 4096 * sizeof(float), stream);
  fc_partial<<<dim3(64, 4), 256, 0, stream>>>(h1, fc2_w, h2, 4096, 4096, 1024);
  bias_relu_kernel<<<128, 256, 0, stream>>>(h2, fc2_b, 4096);
  hipMemsetAsync(d_out, 0, (size_t)out_size * sizeof(float), stream);
  fc3_kernel<<<32, 320, 0, stream>>>(h2, fc3_w, fc3_b, (float*)d_out);
}

// Round 5
// 2432.126 us; speedup vs baseline: 1.0160x; 1.0160x over previous
//
#include <hip/hip_runtime.h>
#include <cstdint>
#include <cstddef>

#define CMID 512

typedef __bf16 bf16x8 __attribute__((ext_vector_type(8)));
typedef float  f32x4  __attribute__((ext_vector_type(4)));

__device__ __forceinline__ ushort f2bf(float v) {
  unsigned u = __float_as_uint(v);
  unsigned r = (u + 0x7fffu + ((u >> 16) & 1u)) >> 16;   // RNE
  return (ushort)r;
}

// async global->LDS DMA, 16B per lane; LDS dest must be wave-uniform base,
// lane i lands at base + i*16 (linear). Global src IS per-lane.
__device__ __forceinline__ void async_copy16(void* lds, const void* g) {
  __builtin_amdgcn_global_load_lds(
      (const __attribute__((address_space(1))) unsigned int*)g,
      (__attribute__((address_space(3))) unsigned int*)lds, 16, 0, 0);
}

// ---- W [27][Cin][512] f32  ->  wT [27][512][Cin] bf16 ----------------------
__global__ __launch_bounds__(256) void transpose_w_kernel(
    const float* __restrict__ W, ushort* __restrict__ wT, int Cin)
{
  __shared__ float tile[32][33];
  int k = blockIdx.z;
  int ci0 = blockIdx.x * 32, co0 = blockIdx.y * 32;
  int tx = threadIdx.x & 31, ty = threadIdx.x >> 5;
  const float* src = W + ((size_t)k * Cin + ci0) * CMID + co0;
  for (int r = ty; r < 32; r += 8)
    tile[r][tx] = src[(size_t)r * CMID + tx];
  __syncthreads();
  ushort* dst = wT + ((size_t)k * CMID + co0) * Cin + ci0;
  for (int r = ty; r < 32; r += 8)
    dst[(size_t)r * Cin + tx] = f2bf(tile[tx][r]);
}

// ---- build inverse kernel map: inv[k][o] = in_idx (or -1) -----------------
__global__ __launch_bounds__(256) void build_inv_kernel(
    const int* __restrict__ in_map, const int* __restrict__ out_map,
    int* __restrict__ inv, int P, int n_out)
{
  int i = blockIdx.x * 256 + threadIdx.x;
  if (i >= 27 * P) return;
  int o = out_map[i];
  if (o < n_out) inv[(size_t)(i / P) * n_out + o] = in_map[i];
}

// ---- OUTPUT-STATIONARY conv (level 2) -------------------------------------
// Round-5: z=1 (full 27x512 reduction per block) -> output written ONCE:
// plain stores (no atomics, no pre-memset). BN stats (sum/sumsq per column)
// fused into the epilogue via q-lane shfl reduce + atomicAdd into stats[]
// (padding rows contribute exactly 0: zrow -> zero A -> zero acc).
// XCD group swizzle kept: all 4 j0-blocks of one o-group on one XCD so the
// 27x128-row A-gather is fetched once per group (FETCH 637->330 MB, r4).
// Grid: 1-D, 32*ceil(G/8), G = ceil(n_out/128).
__global__ __launch_bounds__(256, 4) void conv_os(
    const ushort* __restrict__ x, const ushort* __restrict__ wT,
    const int* __restrict__ inv, float* __restrict__ out,
    float* __restrict__ stats, int n_out, int C_in, int zrow)
{
  const int G   = (n_out + 127) >> 7;
  const int b   = (int)blockIdx.x;
  const int xcd = b & 7;
  const int tt  = b >> 3;
  const int gh  = tt >> 2;
  const int ii  = tt & 3;
  const int g   = gh * 8 + xcd;
  if (g >= G) return;                    // tail pad (uniform per block)

  const int o0  = g * 128;
  const int j0  = ii * 128;
  const int t   = threadIdx.x;

  __shared__ int in_s[128];
  __shared__ ushort A_s[128][64];        // linear: DMA dest (1KB/instr/wave)
  __shared__ ushort B_s[128][64];

  const int lane = t & 63;
  const int wv   = t >> 6;
  const int wm   = (wv & 1) * 64;
  const int wn   = (wv >> 1) * 64;
  const int ml   = lane & 15;
  const int q    = lane >> 4;
  const int srow = lane >> 3;            // row-within-DMA-instr 0..7
  const int gch  = (lane & 7) ^ srow;    // swizzled source chunk (16B units)

  f32x4 acc[4][4] = {};

  for (int k = 0; k < 27; ++k) {
    if (t < 128) {
      int o = o0 + t;
      int s = (o < n_out) ? inv[(size_t)k * n_out + o] : -1;
      in_s[t] = (s >= 0) ? s : zrow;     // zrow is a zeroed feature row
    }
    __syncthreads();

    const ushort* wk = wT + ((size_t)k * CMID + j0) * C_in;
    const ushort* abase[4];
    const ushort* bbase[4];
#pragma unroll
    for (int j = 0; j < 4; ++j) {
      int row = wv * 32 + j * 8 + srow;
      abase[j] = x  + (size_t)in_s[row] * C_in + gch * 8;
      bbase[j] = wk + (size_t)row       * C_in + gch * 8;
    }

    for (int kb = 0; kb < 512; kb += 64) {
#pragma unroll
      for (int j = 0; j < 4; ++j) {
        async_copy16(&A_s[wv * 32 + j * 8][0], abase[j] + kb);
        async_copy16(&B_s[wv * 32 + j * 8][0], bbase[j] + kb);
      }
      __syncthreads();                   // compiler drains vmcnt before barrier
#pragma unroll
      for (int ks = 0; ks < 2; ++ks) {
        const int c = ((ks << 2) | q) ^ (ml & 7);   // swizzled read chunk
        bf16x8 af[4], bb[4];
#pragma unroll
        for (int mt = 0; mt < 4; ++mt)
          af[mt] = *(const bf16x8*)&A_s[wm + mt * 16 + ml][c << 3];
#pragma unroll
        for (int nt = 0; nt < 4; ++nt)
          bb[nt] = *(const bf16x8*)&B_s[wn + nt * 16 + ml][c << 3];
#pragma unroll
        for (int mt = 0; mt < 4; ++mt)
#pragma unroll
          for (int nt = 0; nt < 4; ++nt)
            acc[mt][nt] = __builtin_amdgcn_mfma_f32_16x16x32_bf16(
                af[mt], bb[nt], acc[mt][nt], 0, 0, 0);
      }
      __syncthreads();                   // guards A_s/B_s overwrite next kb
    }
  }

  // C/D layout: col = lane&15, row = (lane>>4)*4 + reg   [m89-verified]
  // Plain stores (single writer) + fused BN stats.
  float s[4] = {0.f, 0.f, 0.f, 0.f}, ss[4] = {0.f, 0.f, 0.f, 0.f};
#pragma unroll
  for (int mt = 0; mt < 4; ++mt) {
#pragma unroll
    for (int r = 0; r < 4; ++r) {
      int o = o0 + wm + mt * 16 + q * 4 + r;
      if (o < n_out) {
        float* orow = out + (size_t)o * CMID + j0 + wn + ml;
#pragma unroll
        for (int nt = 0; nt < 4; ++nt) orow[nt * 16] = acc[mt][nt][r];
      }
#pragma unroll
      for (int nt = 0; nt < 4; ++nt) {   // OOB rows are exactly zero
        float v = acc[mt][nt][r];
        s[nt] += v; ss[nt] += v * v;
      }
    }
  }
#pragma unroll
  for (int nt = 0; nt < 4; ++nt) {       // reduce over q (lane bits 4,5)
    s[nt]  += __shfl_xor(s[nt], 16);  s[nt]  += __shfl_xor(s[nt], 32);
    ss[nt] += __shfl_xor(ss[nt], 16); ss[nt] += __shfl_xor(ss[nt], 32);
  }
  if (q == 0) {
#pragma unroll
    for (int nt = 0; nt < 4; ++nt) {
      int c = j0 + wn + ml + nt * 16;
      atomicAdd(&stats[c],       s[nt]);
      atomicAdd(&stats[512 + c], ss[nt]);
    }
  }
}

// ---- center conv (level 1, k=13 identity): plain stores = accum init ------
__global__ __launch_bounds__(256, 4) void conv_center(
    const ushort* __restrict__ x, const ushort* __restrict__ wT,
    float* __restrict__ out, int n_out, int C_in)
{
  const int k  = 13;
  const int p0 = blockIdx.x * 128;
  const int j0 = blockIdx.y * 128;
  const int t  = threadIdx.x;

  __shared__ ushort A_s[128][64];
  __shared__ ushort B_s[128][64];

  const int lane = t & 63;
  const int wv   = t >> 6;
  const int wm   = (wv & 1) * 64;
  const int wn   = (wv >> 1) * 64;
  const int ml   = lane & 15;
  const int q    = lane >> 4;
  const int srow = lane >> 3;
  const int gch  = (lane & 7) ^ srow;

  const ushort* wk = wT + ((size_t)k * CMID + j0) * C_in;
  const ushort* abase[4];
  const ushort* bbase[4];
#pragma unroll
  for (int j = 0; j < 4; ++j) {
    int row = wv * 32 + j * 8 + srow;
    int src = p0 + row; if (src >= n_out) src = n_out - 1;
    abase[j] = x  + (size_t)src * C_in + gch * 8;
    bbase[j] = wk + (size_t)row * C_in + gch * 8;
  }

  f32x4 acc[4][4] = {};

  for (int kb = 0; kb < C_in; kb += 64) {
#pragma unroll
    for (int j = 0; j < 4; ++j) {
      async_copy16(&A_s[wv * 32 + j * 8][0], abase[j] + kb);
      async_copy16(&B_s[wv * 32 + j * 8][0], bbase[j] + kb);
    }
    __syncthreads();
#pragma unroll
    for (int ks = 0; ks < 2; ++ks) {
      const int c = ((ks << 2) | q) ^ (ml & 7);
      bf16x8 af[4], bb[4];
#pragma unroll
      for (int mt = 0; mt < 4; ++mt)
        af[mt] = *(const bf16x8*)&A_s[wm + mt * 16 + ml][c << 3];
#pragma unroll
      for (int nt = 0; nt < 4; ++nt)
        bb[nt] = *(const bf16x8*)&B_s[wn + nt * 16 + ml][c << 3];
#pragma unroll
      for (int mt = 0; mt < 4; ++mt)
#pragma unroll
        for (int nt = 0; nt < 4; ++nt)
          acc[mt][nt] = __builtin_amdgcn_mfma_f32_16x16x32_bf16(
              af[mt], bb[nt], acc[mt][nt], 0, 0, 0);
    }
    __syncthreads();
  }

#pragma unroll
  for (int mt = 0; mt < 4; ++mt) {
#pragma unroll
    for (int r = 0; r < 4; ++r) {
      int o = p0 + wm + mt * 16 + q * 4 + r;
      if (o < n_out) {
        float* orow = out + (size_t)o * CMID + j0 + wn + ml;
#pragma unroll
        for (int nt = 0; nt < 4; ++nt) orow[nt * 16] = acc[mt][nt][r];
      }
    }
  }
}

// ---- level-1 off-center scatter conv (round-3 form: one offset/block.z) ---
// x-tile order staggered per z-slice to decorrelate atomic regions.
__global__ __launch_bounds__(256, 4) void conv_scatter(
    const ushort* __restrict__ x, const ushort* __restrict__ wT,
    const int* __restrict__ in_map, const int* __restrict__ out_map,
    float* __restrict__ out, int P, int n_out, int C_in)
{
  const int k  = (int)blockIdx.z + (blockIdx.z >= 13 ? 1 : 0);
  const int bx = (int)((blockIdx.x + 5u * blockIdx.z) % gridDim.x);
  const int p0 = bx * 128;
  const int j0 = blockIdx.y * 128;
  const int t  = threadIdx.x;

  __shared__ int out_s[128];
  __shared__ int in_s[128];
  __shared__ int anyv;
  __shared__ ushort A_s[128][64];
  __shared__ ushort B_s[128][64];

  if (t == 0) anyv = 0;
  __syncthreads();
  if (t < 128) {
    int p  = p0 + t;
    int oi = (p < P) ? out_map[(size_t)k * P + p] : n_out;
    int ii = (p < P) ? in_map[(size_t)k * P + p]  : 0;
    out_s[t] = oi; in_s[t] = ii;
    if (oi < n_out) anyv = 1;
  }
  __syncthreads();
  if (!anyv) return;

  const int lane = t & 63;
  const int wv   = t >> 6;
  const int wm   = (wv & 1) * 64;
  const int wn   = (wv >> 1) * 64;
  const int ml   = lane & 15;
  const int q    = lane >> 4;
  const int srow = lane >> 3;
  const int gch  = (lane & 7) ^ srow;

  const ushort* wk = wT + ((size_t)k * CMID + j0) * C_in;
  const ushort* abase[4];
  const ushort* bbase[4];
#pragma unroll
  for (int j = 0; j < 4; ++j) {
    int row = wv * 32 + j * 8 + srow;
    abase[j] = x  + (size_t)in_s[row] * C_in + gch * 8;
    bbase[j] = wk + (size_t)row       * C_in + gch * 8;
  }

  f32x4 acc[4][4] = {};

  for (int kb = 0; kb < C_in; kb += 64) {
#pragma unroll
    for (int j = 0; j < 4; ++j) {
      async_copy16(&A_s[wv * 32 + j * 8][0], abase[j] + kb);
      async_copy16(&B_s[wv * 32 + j * 8][0], bbase[j] + kb);
    }
    __syncthreads();
#pragma unroll
    for (int ks = 0; ks < 2; ++ks) {
      const int c = ((ks << 2) | q) ^ (ml & 7);
      bf16x8 af[4], bb[4];
#pragma unroll
      for (int mt = 0; mt < 4; ++mt)
        af[mt] = *(const bf16x8*)&A_s[wm + mt * 16 + ml][c << 3];
#pragma unroll
      for (int nt = 0; nt < 4; ++nt)
        bb[nt] = *(const bf16x8*)&B_s[wn + nt * 16 + ml][c << 3];
#pragma unroll
      for (int mt = 0; mt < 4; ++mt)
#pragma unroll
        for (int nt = 0; nt < 4; ++nt)
          acc[mt][nt] = __builtin_amdgcn_mfma_f32_16x16x32_bf16(
              af[mt], bb[nt], acc[mt][nt], 0, 0, 0);
    }
    __syncthreads();
  }

#pragma unroll
  for (int mt = 0; mt < 4; ++mt) {
#pragma unroll
    for (int r = 0; r < 4; ++r) {
      int o = out_s[wm + mt * 16 + q * 4 + r];
      if (o < n_out) {
        float* orow = out + (size_t)o * CMID + j0 + wn + ml;
#pragma unroll
        for (int nt = 0; nt < 4; ++nt)
          atomicAdd(orow + nt * 16, acc[mt][nt][r]);
      }
    }
  }
}

// ---- BN stats (fp32 accum) — level-1 layers only --------------------------
__global__ __launch_bounds__(256) void bn_stats_kernel(
    const float* __restrict__ x, float* __restrict__ stats, int n)
{
  int t = threadIdx.x;
  float s0 = 0.f, q0 = 0.f, s1 = 0.f, q1 = 0.f;
  for (int r = blockIdx.x; r < n; r += gridDim.x) {
    const float* row = x + (size_t)r * CMID;
    float v0 = row[t];
    float v1 = row[t + 256];
    s0 += v0; q0 += v0 * v0;
    s1 += v1; q1 += v1 * v1;
  }
  atomicAdd(&stats[t],        s0);
  atomicAdd(&stats[512 + t],  q0);
  atomicAdd(&stats[t + 256],  s1);
  atomicAdd(&stats[768 + t],  q1);
}

// ---- BN apply + ReLU, fp32 in -> bf16 out; optional fused max-pool --------
__global__ __launch_bounds__(256) void bn_apply_cast(
    const float* __restrict__ x, const float* __restrict__ stats,
    const float* __restrict__ gamma, const float* __restrict__ beta,
    ushort* __restrict__ y, long total, float inv_n,
    const int* __restrict__ pidx, float* __restrict__ pout)
{
  long stride = (long)gridDim.x * 256;
  for (long i = (long)blockIdx.x * 256 + threadIdx.x; i < total; i += stride) {
    int c = (int)(i & 511);
    float mu  = stats[c] * inv_n;
    float var = stats[512 + c] * inv_n - mu * mu;
    float g   = gamma[c] * rsqrtf(var + 1e-5f);
    float v   = (x[i] - mu) * g + beta[c];
    ushort yv = f2bf(v > 0.f ? v : 0.f);
    y[i] = yv;
    if (pout) {
      int r = (int)(i >> 9);
      int o = pidx[r];
      atomicMax((int*)(pout + (size_t)o * CMID + c), ((int)yv) << 16);
    }
  }
}

// ---- pools (post-ReLU >= 0 -> int-punned atomicMax), grid-stride ----------
__global__ __launch_bounds__(256) void pool_max_bf16(
    const ushort* __restrict__ x, const int* __restrict__ idx,
    float* __restrict__ out, long total)
{
  long stride = (long)gridDim.x * 256;
  for (long i = (long)blockIdx.x * 256 + threadIdx.x; i < total; i += stride) {
    int r = (int)(i >> 9);
    int c = (int)(i & 511);
    int o = idx[r];
    int bits = ((int)x[i]) << 16;
    atomicMax((int*)(out + (size_t)o * CMID + c), bits);
  }
}

__global__ __launch_bounds__(256) void pool_max_f32(
    const float* __restrict__ x, const int* __restrict__ idx,
    float* __restrict__ out, long total)
{
  long stride = (long)gridDim.x * 256;
  for (long i = (long)blockIdx.x * 256 + threadIdx.x; i < total; i += stride) {
    int r = (int)(i >> 9);
    int c = (int)(i & 511);
    int o = idx[r];
    atomicMax((int*)(out + (size_t)o * CMID + c), __float_as_int(x[i]));
  }
}

// ---- cast fp32 -> bf16, grid-stride ---------------------------------------
__global__ __launch_bounds__(256) void cast_f32_bf16_kernel(
    const float* __restrict__ in, ushort* __restrict__ out, long n)
{
  long stride = (long)gridDim.x * 256;
  for (long i = (long)blockIdx.x * 256 + threadIdx.x; i < n; i += stride)
    out[i] = f2bf(in[i]);
}

// ---- FC: partial GEMM with K-split ----------------------------------------
__global__ __launch_bounds__(256) void fc_partial(
    const float* __restrict__ x, const float* __restrict__ W,
    float* __restrict__ h, int K, int N, int Kc)
{
  __shared__ float xs[8][1024];
  int t  = threadIdx.x;
  int j  = blockIdx.x * 64 + (t & 63);
  int bg = t >> 6;
  int k0 = blockIdx.y * Kc;
  for (int i = t; i < 8 * Kc; i += 256) {
    int b = i / Kc; int kk = i - b * Kc;
    xs[b][kk] = x[(size_t)b * K + k0 + kk];
  }
  __syncthreads();
  float a0 = 0.f, a1 = 0.f;
  for (int kk = 0; kk < Kc; ++kk) {
    float wv = W[(size_t)(k0 + kk) * N + j];
    a0 += xs[bg][kk] * wv;
    a1 += xs[bg + 4][kk] * wv;
  }
  atomicAdd(&h[(size_t)bg * N + j], a0);
  atomicAdd(&h[(size_t)(bg + 4) * N + j], a1);
}

__global__ __launch_bounds__(256) void bias_relu_kernel(
    float* __restrict__ h, const float* __restrict__ bias, int N)
{
  int i = blockIdx.x * 256 + threadIdx.x;
  if (i >= 8 * N) return;
  float v = h[i] + bias[i % N];
  h[i] = v > 0.f ? v : 0.f;
}

// ---- FC3 -------------------------------------------------------------------
__global__ __launch_bounds__(320) void fc3_kernel(
    const float* __restrict__ x, const float* __restrict__ W,
    const float* __restrict__ bias, float* __restrict__ out)
{
  int t = threadIdx.x;
  int j = t % 40;
  int b = t / 40;
  int kb = blockIdx.x * 128;
  float acc = 0.f;
#pragma unroll 8
  for (int kk = 0; kk < 128; ++kk)
    acc += x[(size_t)b * 4096 + kb + kk] * W[(size_t)(kb + kk) * 40 + j];
  if (blockIdx.x == 0) acc += bias[j];
  atomicAdd(&out[(size_t)b * 40 + j], acc);
}

// ---------------------------------------------------------------------------
extern "C" void kernel_launch(void* const* d_in, const int* in_sizes, int n_in,
                              void* d_out, int out_size, void* d_ws, size_t ws_size,
                              hipStream_t stream)
{
  const float* feats  = (const float*)d_in[0];
  const float* wts[6] = {(const float*)d_in[1], (const float*)d_in[2],
                         (const float*)d_in[3], (const float*)d_in[4],
                         (const float*)d_in[5], (const float*)d_in[6]};
  const float* bn_g   = (const float*)d_in[7];
  const float* bn_b   = (const float*)d_in[8];
  const float* fc1_w  = (const float*)d_in[9];
  const float* fc1_b  = (const float*)d_in[10];
  const float* fc2_w  = (const float*)d_in[11];
  const float* fc2_b  = (const float*)d_in[12];
  const float* fc3_w  = (const float*)d_in[13];
  const float* fc3_b  = (const float*)d_in[14];
  const int* map1_in  = (const int*)d_in[15];
  const int* map1_out = (const int*)d_in[16];
  const int* map2_in  = (const int*)d_in[17];
  const int* map2_out = (const int*)d_in[18];
  const int* pool1_idx = (const int*)d_in[19];
  const int* pool2_idx = (const int*)d_in[20];
  const int* batch_idx = (const int*)d_in[21];

  const int N1 = in_sizes[0] / 256;
  const int P1 = in_sizes[15] / 27;
  const int P2 = in_sizes[17] / 27;
  const int n2 = in_sizes[20];
  const int n3 = in_sizes[21];

  // workspace layout (~126.3 MiB used of >=128):
  //  [0,64)    accum fp32 (N1 x 512) / pool1 target
  //  [64,96)   fbuf bf16 features (post-BN); row n2 kept zero (conv_os zrow)
  //  [96,112)  featsb bf16 conv1 input; later: pooled2f (fp32, <=8.5 MB)
  //            + inv2 (27 x n2 ints, ~2.3 MB) at +9 MiB
  //  [112,126) wTbuf bf16 transposed weights
  //  [126,..)  stats + FC scratch
  const size_t MB = (size_t)1 << 20;
  char* wsb = (char*)d_ws;
  float*  accum   = (float*)wsb;
  ushort* fbuf    = (ushort*)(wsb + 64 * MB);
  ushort* featsb  = (ushort*)(wsb + 96 * MB);
  int*    inv2    = (int*)(wsb + 105 * MB);
  ushort* wTbuf   = (ushort*)(wsb + 112 * MB);
  float*  stats   = (float*)(wsb + 126 * MB);
  float*  gpooled = stats + 1024;
  float*  h1      = gpooled + 8 * 512;
  float*  h2      = h1 + 8 * 4096;
  float*  pooled2f = (float*)featsb;

  auto gsb = [](long tot) {                 // grid-stride block count, G11 cap
    long b = (tot + 255) / 256;
    return (int)(b < 2048 ? b : 2048);
  };

  long nf = (long)N1 * 256;
  cast_f32_bf16_kernel<<<gsb(nf), 256, 0, stream>>>(feats, featsb, nf);

  // level-1 conv: center (plain stores, inits accum) + 26 scatter offsets
  auto conv1 = [&](const ushort* xin, const float* w, int Cin) {
    transpose_w_kernel<<<dim3(Cin / 32, CMID / 32, 27), 256, 0, stream>>>(w, wTbuf, Cin);
    conv_center<<<dim3((N1 + 127) / 128, 4, 1), 256, 0, stream>>>(
        xin, wTbuf, accum, N1, Cin);
    conv_scatter<<<dim3((P1 + 127) / 128, 4, 26), 256, 0, stream>>>(
        xin, wTbuf, map1_in, map1_out, accum, P1, N1, Cin);
  };
  // level-2 conv: output-stationary z=1, plain stores, fused BN stats
  const int G2 = (n2 + 127) / 128;
  auto conv2 = [&](const ushort* xin, const float* w) {
    transpose_w_kernel<<<dim3(512 / 32, CMID / 32, 27), 256, 0, stream>>>(w, wTbuf, 512);
    hipMemsetAsync(stats, 0, 1024 * sizeof(float), stream);
    conv_os<<<32 * ((G2 + 7) / 8), 256, 0, stream>>>(
        xin, wTbuf, inv2, accum, stats, n2, 512, n2);
  };
  // level-1 bn (stats via separate pass)
  auto bn1 = [&](int layer) {
    hipMemsetAsync(stats, 0, 1024 * sizeof(float), stream);
    bn_stats_kernel<<<1024, 256, 0, stream>>>(accum, stats, N1);
    long tot = (long)N1 * CMID;
    bn_apply_cast<<<gsb(tot), 256, 0, stream>>>(
        accum, stats, bn_g + layer * CMID, bn_b + layer * CMID, fbuf, tot,
        1.0f / N1, nullptr, nullptr);
  };
  // level-2 bn apply only (stats already produced by conv_os epilogue)
  auto bn2 = [&](int layer, const int* pidx, float* pout) {
    long tot = (long)n2 * CMID;
    bn_apply_cast<<<gsb(tot), 256, 0, stream>>>(
        accum, stats, bn_g + layer * CMID, bn_b + layer * CMID, fbuf, tot,
        1.0f / n2, pidx, pout);
  };

  // --- level 1 ---
  conv1(featsb, wts[0], 256); bn1(0);
  conv1(fbuf,   wts[1], 512); bn1(1);
  conv1(fbuf,   wts[2], 512); bn1(2);

  // --- pool 1: fbuf(N1) -> accum(n2, fp32) -> fbuf bf16 ---
  long t1 = (long)N1 * CMID;
  long t2 = (long)n2 * CMID;
  hipMemsetAsync(accum, 0, (size_t)n2 * CMID * sizeof(float), stream);
  pool_max_bf16<<<gsb(t1), 256, 0, stream>>>(fbuf, pool1_idx, accum, t1);
  cast_f32_bf16_kernel<<<gsb(t2), 256, 0, stream>>>(accum, fbuf, t2);
  // zero row n2 of fbuf: conv_os redirects invalid gathers here (DMA can't
  // predicate). bn_apply_cast only writes rows < n2, so it stays zero.
  hipMemsetAsync(fbuf + (size_t)n2 * CMID, 0, CMID * sizeof(ushort), stream);

  // --- build level-2 inverse map (once; reused by all 3 convs) ---
  hipMemsetAsync(inv2, 0xFF, (size_t)27 * n2 * sizeof(int), stream);
  build_inv_kernel<<<(27 * P2 + 255) / 256, 256, 0, stream>>>(
      map2_in, map2_out, inv2, P2, n2);

  // --- level 2 (output-stationary); pool2 fused into last bn ---
  conv2(fbuf, wts[3]); bn2(3, nullptr, nullptr);
  conv2(fbuf, wts[4]); bn2(4, nullptr, nullptr);
  conv2(fbuf, wts[5]);
  hipMemsetAsync(pooled2f, 0, (size_t)n3 * CMID * sizeof(float), stream);
  bn2(5, pool2_idx, pooled2f);      // bn + ReLU + cast + pool2 in one pass

  // --- global max pool ---
  long t3 = (long)n3 * CMID;
  hipMemsetAsync(gpooled, 0, 8 * CMID * sizeof(float), stream);
  pool_max_f32<<<gsb(t3), 256, 0, stream>>>(pooled2f, batch_idx, gpooled, t3);

  // --- FC head ---
  hipMemsetAsync(h1, 0, 8 * 4096 * sizeof(float), stream);
  fc_partial<<<dim3(64, 1), 256, 0, stream>>>(gpooled, fc1_w, h1, 512, 4096, 512);
  bias_relu_kernel<<<128, 256, 0, stream>>>(h1, fc1_b, 4096);
  hipMemsetAsync(h2, 0, 8 * 4096 * sizeof(float), stream);
  fc_partial<<<dim3(64, 4), 256, 0, stream>>>(h1, fc2_w, h2, 4096, 4096, 1024);
  bias_relu_kernel<<<128, 256, 0, stream>>>(h2, fc2_b, 4096);
  hipMemsetAsync(d_out, 0, (size_t)out_size * sizeof(float), stream);
  fc3_kernel<<<32, 320, 0, stream>>>(h2, fc3_w, fc3_b, (float*)d_out);
}